// Round 5
// baseline (237.848 us; speedup 1.0000x reference)
//
#include <hip/hip_runtime.h>

#define BB 4
#define HH 1024
#define WW 1024
#define K2 9
#define PAD 1

#define TW 64             // tile width (2 px per thread along w)
#define TH 8              // tile height
#define R  12             // halo radius (~6 sigma of offset)
#define RW (TW + 2*R)     // 88
#define RH (TH + 2*R)     // 32
#define RSZ (RW * RH)     // 2816 = 11 * 256

typedef float f32x2 __attribute__((ext_vector_type(2)));

__global__ __launch_bounds__(256, 4) void dcn_kernel(
    const float* __restrict__ init_dem,   // [B,1,H,W]
    const float* __restrict__ weight,     // [B,K2,H,W]
    const float* __restrict__ offset,     // [B,2*K2,H,W]
    const float* __restrict__ wk,         // [K2]
    const float* __restrict__ bias,       // [1]
    float* __restrict__ out)              // [B,1,H,W]
{
    __shared__ float region[RSZ];

    const int HW = HH * WW;

    // batch pinned to an XCD pair (blockIdx % 8 -> XCD heuristic)
    int i    = blockIdx.x;
    int b    = (i & 7) >> 1;
    int widx = ((i >> 3) << 1) | (i & 1);   // 0..2047, bijective
    int tile_w = widx & 15;                 // WW/TW = 16
    int tile_h = widx >> 4;                 // HH/TH = 128
    int w0 = tile_w * TW;
    int h0 = tile_h * TH;

    const float* img = init_dem + (size_t)b * HW;

    // ---- stage image region (halo included, zeros outside image) ----
    int tid = threadIdx.x;
#pragma unroll
    for (int it = 0; it < RSZ / 256; ++it) {
        int e = tid + it * 256;
        int r = e / RW;
        int c = e - r * RW;
        int gy = h0 - R + r;
        int gx = w0 - R + c;
        float v = 0.f;
        if ((unsigned)gy < (unsigned)HH && (unsigned)gx < (unsigned)WW)
            v = img[gy * WW + gx];
        region[e] = v;
    }
    __syncthreads();

    const int tx2 = (tid & 31) << 1;        // 0,2,...,62
    const int ty  = tid >> 5;               // 0..7
    const int h   = h0 + ty;
    const int w   = w0 + tx2;
    const int rem = h * WW + w;

    const float* wq = weight + (size_t)b * K2 * HW + rem;
    const float* oq = offset + (size_t)b * 2 * K2 * HW + rem;

    // ---- batch ALL stream loads; sched_barrier keeps them grouped (27 in flight) ----
    f32x2 wt2[K2], dy2[K2], dx2[K2];
#pragma unroll
    for (int k = 0; k < K2; ++k) {
        wt2[k] = __builtin_nontemporal_load((const f32x2*)(wq + (size_t)k * HW));
        dy2[k] = __builtin_nontemporal_load((const f32x2*)(oq + (size_t)(2 * k) * HW));
        dx2[k] = __builtin_nontemporal_load((const f32x2*)(oq + (size_t)(2 * k + 1) * HW));
    }
    __builtin_amdgcn_sched_barrier(0);

    float accA[2] = {0.f, 0.f};   // sum samp*wk*wt
    float accB[2] = {0.f, 0.f};   // sum samp*wk
    float msum[2] = {0.f, 0.f};   // sum wt

#pragma unroll
    for (int k = 0; k < K2; ++k) {
        const float wkk = wk[k];
        const int ky = k / 3, kx = k % 3;
#pragma unroll
        for (int p = 0; p < 2; ++p) {
            float wt = wt2[k][p], dy = dy2[k][p], dx = dx2[k][p];
            msum[p] += wt;

            float ys = (float)(h - PAD + ky) + dy;
            float xs = (float)(w + p - PAD + kx) + dx;

            float y0f = floorf(ys);
            float x0f = floorf(xs);
            float wy1 = ys - y0f;
            float wx1 = xs - x0f;
            float wy0 = 1.f - wy1;
            float wx0 = 1.f - wx1;

            int y0g = (int)y0f;
            int x0g = (int)x0f;
            int y0l = y0g - (h0 - R);
            int x0l = x0g - (w0 - R);

            float v00, v01, v10, v11;
            bool fast = (y0l >= 0) & (y0l < RH - 1) & (x0l >= 0) & (x0l < RW - 1);
            if (fast) {
                int base = y0l * RW + x0l;
                v00 = region[base];
                v01 = region[base + 1];
                v10 = region[base + RW];
                v11 = region[base + RW + 1];
            } else {
                int y1g = y0g + 1;
                int x1g = x0g + 1;
                bool y0v = (y0g >= 0) & (y0g < HH);
                bool y1v = (y1g >= 0) & (y1g < HH);
                bool x0v = (x0g >= 0) & (x0g < WW);
                bool x1v = (x1g >= 0) & (x1g < WW);
                int yc0 = min(max(y0g, 0), HH - 1);
                int yc1 = min(max(y1g, 0), HH - 1);
                int xc0 = min(max(x0g, 0), WW - 1);
                int xc1 = min(max(x1g, 0), WW - 1);
                v00 = (y0v & x0v) ? img[(size_t)yc0 * WW + xc0] : 0.f;
                v01 = (y0v & x1v) ? img[(size_t)yc0 * WW + xc1] : 0.f;
                v10 = (y1v & x0v) ? img[(size_t)yc1 * WW + xc0] : 0.f;
                v11 = (y1v & x1v) ? img[(size_t)yc1 * WW + xc1] : 0.f;
            }

            float samp = wy0 * (wx0 * v00 + wx1 * v01)
                       + wy1 * (wx0 * v10 + wx1 * v11);
            float sw = samp * wkk;
            accA[p] += sw * wt;
            accB[p] += sw;
        }
    }

    const float bval = bias[0];
    f32x2 res;
#pragma unroll
    for (int p = 0; p < 2; ++p) {
        float mean  = msum[p] * (1.0f / K2);
        float resid = region[(ty + R) * RW + (tx2 + R + p)];
        res[p] = accA[p] - mean * accB[p] + bval + resid;
    }
    __builtin_nontemporal_store(res, (f32x2*)(out + (size_t)b * HW + rem));
}

extern "C" void kernel_launch(void* const* d_in, const int* in_sizes, int n_in,
                              void* d_out, int out_size, void* d_ws, size_t ws_size,
                              hipStream_t stream) {
    const float* init_dem = (const float*)d_in[0];
    const float* weight   = (const float*)d_in[1];
    const float* offset   = (const float*)d_in[2];
    const float* wk       = (const float*)d_in[3];
    const float* bias     = (const float*)d_in[4];
    float* out            = (float*)d_out;

    const int nblocks = BB * (WW / TW) * (HH / TH);   // 4*16*128 = 8192
    dcn_kernel<<<dim3(nblocks), dim3(256), 0, stream>>>(init_dem, weight, offset, wk, bias, out);
}

// Round 6
// 117.032 us; speedup vs baseline: 2.0323x; 2.0323x over previous
//
#include <hip/hip_runtime.h>

#define BB 4
#define HH 1024
#define WW 1024
#define K2 9
#define PAD 1

#define R   12            // halo radius (covers ~6 sigma offsets)
#define TW  64            // tile width
#define TH  8             // tile height (2 rows per thread)
#define RW  (TW + 2*R)    // 88
#define RH  (TH + 2*R)    // 32
#define RSZ (RW * RH)     // 2816 = 11 * 256

__global__ __launch_bounds__(256) void dcn_kernel(
    const float* __restrict__ init_dem,   // [B,1,H,W]
    const float* __restrict__ weight,     // [B,K2,H,W]
    const float* __restrict__ offset,     // [B,2*K2,H,W]
    const float* __restrict__ wk,         // [K2]
    const float* __restrict__ bias,       // [1]
    float* __restrict__ out)              // [B,1,H,W]
{
    __shared__ float region[RSZ];

    const int HW = HH * WW;

    // batch pinned to an XCD pair (blockIdx % 8 -> XCD heuristic)
    int i    = blockIdx.x;
    int b    = (i & 7) >> 1;
    int widx = ((i >> 3) << 1) | (i & 1);     // 0 .. 2047, bijective
    int tile_w = widx & 15;                   // W/TW = 16
    int tile_h = widx >> 4;                   // H/TH = 128
    int w0 = tile_w * TW;
    int h0 = tile_h * TH;

    const float* img = init_dem + (size_t)b * HW;

    // ---- stage image region (halo included, zeros outside image) ----
    int tid = threadIdx.x;
#pragma unroll
    for (int it = 0; it < RSZ / 256; ++it) {
        int e = tid + it * 256;
        int r = e / RW;
        int c = e - r * RW;
        int gy = h0 - R + r;
        int gx = w0 - R + c;
        float v = 0.f;
        if ((unsigned)gy < (unsigned)HH && (unsigned)gx < (unsigned)WW)
            v = img[gy * WW + gx];
        region[e] = v;
    }
    __syncthreads();

    const int tx = tid & 63;
    const int ty = tid >> 6;
    const float bval = bias[0];

#pragma unroll
    for (int p = 0; p < 2; ++p) {
        int h = h0 + ty + p * 4;
        int w = w0 + tx;
        int rem = h * WW + w;

        const float* wq = weight + (size_t)b * K2 * HW + rem;
        const float* oq = offset + (size_t)b * 2 * K2 * HW + rem;

        float accA = 0.f;   // sum samp*wk*wt
        float accB = 0.f;   // sum samp*wk
        float msum = 0.f;   // sum wt

        // process taps in chunks of 3: 9 stream loads batched -> in flight together
#pragma unroll
        for (int kg = 0; kg < 3; ++kg) {
            float wt[3], dy[3], dx[3];
#pragma unroll
            for (int j = 0; j < 3; ++j) {
                int k = kg * 3 + j;
                wt[j] = __builtin_nontemporal_load(wq + (size_t)k * HW);
                dy[j] = __builtin_nontemporal_load(oq + (size_t)(2 * k) * HW);
                dx[j] = __builtin_nontemporal_load(oq + (size_t)(2 * k + 1) * HW);
            }

#pragma unroll
            for (int j = 0; j < 3; ++j) {
                int k = kg * 3 + j;
                int ky = k / 3, kx = k % 3;
                msum += wt[j];

                float ys = (float)(h - PAD + ky) + dy[j];
                float xs = (float)(w - PAD + kx) + dx[j];

                float y0f = floorf(ys);
                float x0f = floorf(xs);
                float wy1 = ys - y0f;
                float wx1 = xs - x0f;
                float wy0 = 1.f - wy1;
                float wx0 = 1.f - wx1;

                int y0g = (int)y0f;
                int x0g = (int)x0f;
                int y0l = y0g - (h0 - R);
                int x0l = x0g - (w0 - R);

                float v00, v01, v10, v11;
                bool fast = (y0l >= 0) & (y0l < RH - 1) & (x0l >= 0) & (x0l < RW - 1);
                if (fast) {
                    int base = y0l * RW + x0l;
                    v00 = region[base];
                    v01 = region[base + 1];
                    v10 = region[base + RW];
                    v11 = region[base + RW + 1];
                } else {
                    int y1g = y0g + 1;
                    int x1g = x0g + 1;
                    bool y0v = (y0g >= 0) & (y0g < HH);
                    bool y1v = (y1g >= 0) & (y1g < HH);
                    bool x0v = (x0g >= 0) & (x0g < WW);
                    bool x1v = (x1g >= 0) & (x1g < WW);
                    int yc0 = min(max(y0g, 0), HH - 1);
                    int yc1 = min(max(y1g, 0), HH - 1);
                    int xc0 = min(max(x0g, 0), WW - 1);
                    int xc1 = min(max(x1g, 0), WW - 1);
                    v00 = (y0v & x0v) ? img[(size_t)yc0 * WW + xc0] : 0.f;
                    v01 = (y0v & x1v) ? img[(size_t)yc0 * WW + xc1] : 0.f;
                    v10 = (y1v & x0v) ? img[(size_t)yc1 * WW + xc0] : 0.f;
                    v11 = (y1v & x1v) ? img[(size_t)yc1 * WW + xc1] : 0.f;
                }

                float samp = wy0 * (wx0 * v00 + wx1 * v01)
                           + wy1 * (wx0 * v10 + wx1 * v11);
                float sw = samp * wk[k];
                accA += sw * wt[j];
                accB += sw;
            }
        }

        float mean  = msum * (1.0f / K2);
        float resid = region[(ty + p * 4 + R) * RW + (tx + R)];
        float rres  = accA - mean * accB + bval + resid;
        __builtin_nontemporal_store(rres, out + (size_t)b * HW + rem);
    }
}

extern "C" void kernel_launch(void* const* d_in, const int* in_sizes, int n_in,
                              void* d_out, int out_size, void* d_ws, size_t ws_size,
                              hipStream_t stream) {
    const float* init_dem = (const float*)d_in[0];
    const float* weight   = (const float*)d_in[1];
    const float* offset   = (const float*)d_in[2];
    const float* wk       = (const float*)d_in[3];
    const float* bias     = (const float*)d_in[4];
    float* out            = (float*)d_out;

    const int nblocks = BB * (WW / TW) * (HH / TH);   // 4*16*128 = 8192
    dcn_kernel<<<dim3(nblocks), dim3(256), 0, stream>>>(init_dem, weight, offset, wk, bias, out);
}

// Round 7
// 102.471 us; speedup vs baseline: 2.3211x; 1.1421x over previous
//
#include <hip/hip_runtime.h>

#define BB 4
#define HH 1024
#define WW 1024
#define K2 9
#define PAD 1

#define R   12            // halo radius (covers ~6 sigma offsets)
#define TW  64            // tile width
#define TH  8             // tile height (2 rows per thread)
#define RW  (TW + 2*R)    // 88
#define RH  (TH + 2*R)    // 32
#define RSZ (RW * RH)     // 2816 = 11 * 256

__global__ __launch_bounds__(256) void dcn_kernel(
    const float* __restrict__ init_dem,   // [B,1,H,W]
    const float* __restrict__ weight,     // [B,K2,H,W]
    const float* __restrict__ offset,     // [B,2*K2,H,W]
    const float* __restrict__ wk,         // [K2]
    const float* __restrict__ bias,       // [1]
    float* __restrict__ out)              // [B,1,H,W]
{
    __shared__ float region[RSZ];

    const int HW = HH * WW;

    // batch pinned to an XCD pair (blockIdx % 8 -> XCD heuristic)
    int i    = blockIdx.x;
    int b    = (i & 7) >> 1;
    int widx = ((i >> 3) << 1) | (i & 1);     // 0 .. 2047, bijective
    int tile_w = widx & 15;                   // W/TW = 16
    int tile_h = widx >> 4;                   // H/TH = 128
    int w0 = tile_w * TW;
    int h0 = tile_h * TH;

    const float* img = init_dem + (size_t)b * HW;

    // ---- stage image region (halo included, zeros outside image) ----
    int tid = threadIdx.x;
#pragma unroll
    for (int it = 0; it < RSZ / 256; ++it) {
        int e = tid + it * 256;
        int r = e / RW;
        int c = e - r * RW;
        int gy = h0 - R + r;
        int gx = w0 - R + c;
        float v = 0.f;
        if ((unsigned)gy < (unsigned)HH && (unsigned)gx < (unsigned)WW)
            v = img[gy * WW + gx];
        region[e] = v;
    }
    __syncthreads();

    const int tx = tid & 63;
    const int ty = tid >> 6;
    const float bval = bias[0];

    float wgt[K2];
#pragma unroll
    for (int k = 0; k < K2; ++k) wgt[k] = wk[k];

#pragma unroll
    for (int p = 0; p < 2; ++p) {
        int h = h0 + ty + p * 4;
        int w = w0 + tx;
        int rem = h * WW + w;

        const float* wq = weight + (size_t)b * K2 * HW + rem;
        const float* oq = offset + (size_t)b * 2 * K2 * HW + rem;

        // batch all 27 stream loads (R3 structure: keep them in flight together)
        float wt[K2], dy[K2], dx[K2];
        float wsum = 0.f;
#pragma unroll
        for (int k = 0; k < K2; ++k) {
            wt[k] = __builtin_nontemporal_load(wq + (size_t)k * HW);
            dy[k] = __builtin_nontemporal_load(oq + (size_t)(2 * k) * HW);
            dx[k] = __builtin_nontemporal_load(oq + (size_t)(2 * k + 1) * HW);
            wsum += wt[k];
        }
        const float mean = wsum * (1.0f / K2);

        // local (region-space) base coords: ysl = ys - (h0 - R), xsl = xs - (w0 - R)
        const float fy = (float)(ty + p * 4 + R - PAD);
        const float fx = (float)(tx + R - PAD);

        float acc = 0.f;
#pragma unroll
        for (int k = 0; k < K2; ++k) {
            const int ky = k / 3, kx = k % 3;

            float ysl = (fy + (float)ky) + dy[k];
            float xsl = (fx + (float)kx) + dx[k];

            float y0f = floorf(ysl);
            float x0f = floorf(xsl);
            float wy1 = ysl - y0f;
            float wx1 = xsl - x0f;
            float wy0 = 1.f - wy1;
            float wx0 = 1.f - wx1;

            int y0l = (int)y0f;
            int x0l = (int)x0f;

            float v00, v01, v10, v11;
            if (((unsigned)y0l < (unsigned)(RH - 1)) &
                ((unsigned)x0l < (unsigned)(RW - 1))) {
                int base = y0l * RW + x0l;
                // paired so the backend merges into 2x ds_read2_b32 (offsets 0/RW, 1/RW+1)
                v00 = region[base];
                v10 = region[base + RW];
                v01 = region[base + 1];
                v11 = region[base + RW + 1];
            } else {
                int y0g = y0l + (h0 - R);
                int x0g = x0l + (w0 - R);
                int y1g = y0g + 1;
                int x1g = x0g + 1;
                bool y0v = (y0g >= 0) & (y0g < HH);
                bool y1v = (y1g >= 0) & (y1g < HH);
                bool x0v = (x0g >= 0) & (x0g < WW);
                bool x1v = (x1g >= 0) & (x1g < WW);
                int yc0 = min(max(y0g, 0), HH - 1);
                int yc1 = min(max(y1g, 0), HH - 1);
                int xc0 = min(max(x0g, 0), WW - 1);
                int xc1 = min(max(x1g, 0), WW - 1);
                v00 = (y0v & x0v) ? img[(size_t)yc0 * WW + xc0] : 0.f;
                v01 = (y0v & x1v) ? img[(size_t)yc0 * WW + xc1] : 0.f;
                v10 = (y1v & x0v) ? img[(size_t)yc1 * WW + xc0] : 0.f;
                v11 = (y1v & x1v) ? img[(size_t)yc1 * WW + xc1] : 0.f;
            }

            float samp = wy0 * (wx0 * v00 + wx1 * v01)
                       + wy1 * (wx0 * v10 + wx1 * v11);
            acc += samp * (wt[k] - mean) * wgt[k];
        }

        float resid = region[(ty + p * 4 + R) * RW + (tx + R)];
        float rres  = acc + bval + resid;
        __builtin_nontemporal_store(rres, out + (size_t)b * HW + rem);
    }
}

extern "C" void kernel_launch(void* const* d_in, const int* in_sizes, int n_in,
                              void* d_out, int out_size, void* d_ws, size_t ws_size,
                              hipStream_t stream) {
    const float* init_dem = (const float*)d_in[0];
    const float* weight   = (const float*)d_in[1];
    const float* offset   = (const float*)d_in[2];
    const float* wk       = (const float*)d_in[3];
    const float* bias     = (const float*)d_in[4];
    float* out            = (float*)d_out;

    const int nblocks = BB * (WW / TW) * (HH / TH);   // 4*16*128 = 8192
    dcn_kernel<<<dim3(nblocks), dim3(256), 0, stream>>>(init_dem, weight, offset, wk, bias, out);
}